// Round 7
// baseline (101.077 us; speedup 1.0000x reference)
//
#include <hip/hip_runtime.h>

#define W      512
#define IMG    (512 * 512)
#define NB     16
#define NPIX   (NB * IMG)

// ---- geometry: 1024 uniform hybrid blocks of 512 threads, 4 blocks/CU ----
// each block: loss streaming for one 8-row slab + exact EDT for the same tile.
// Finer blocks = 4 independent barrier domains per CU (was 2 x 16-wave convoys).
#define TILE_H 8
#define APRON  4
#define LROWS  (TILE_H + 2 * APRON)       // 16
#define BLOCK  512
#define GRID   (NB * (W / TILE_H))        // 1024 == 256 CUs * 4 blocks/CU (100% cap)

struct WS {
    unsigned int vmax[16];        // zeroed each launch; per-batch max int d^2
    float C[NB * W];              // zeroed each launch; C[b,y] = sum_h t*(x-t)^2
    float rows[NB * W];           // w_edt[b, h=b, y] (sqrt'd)
    float4 partial[GRID];         // .x=sum(x-t)^2  .y=sum p*t  .z=sum p  .w=sum t
};
#define MEMSET_BYTES (sizeof(unsigned int) * 16 + sizeof(float) * NB * W)

__device__ __forceinline__ unsigned pk_min_u16(unsigned a, unsigned b) {
    unsigned r; asm("v_pk_min_u16 %0, %1, %2" : "=v"(r) : "v"(a), "v"(b)); return r;
}
__device__ __forceinline__ unsigned pk_max_u16(unsigned a, unsigned b) {
    unsigned r; asm("v_pk_max_u16 %0, %1, %2" : "=v"(r) : "v"(a), "v"(b)); return r;
}

// Exact full-image nearest-zero scan (rare fallback; also handles no-zero case -> BIG)
__device__ int exact_best(const float* __restrict__ img, int h, int y) {
    int best = 100000000;   // reference BIG when no zeros exist
    for (int gh = 0; gh < W; ++gh) {
        int dhh = gh - h;
        if (dhh * dhh >= best) continue;
        const float* rp = img + (gh << 9);
        for (int yy = 0; yy < W; ++yy)
            if (rp[yy] == 0.0f) {
                int dx = yy - y;
                best = min(best, dhh * dhh + dx * dx);
            }
    }
    return best;
}

// Fused kernel: per-block loss streaming + exact EDT tile.
//
// EDT: separable bit-trick. Phase 2 stores CLAMPED d^2 (<=65471) as u16.
// Phase 3: each thread owns a y-pair and 4 output rows; loads the 12-row packed
// column into registers, then 4x9 v_pk_min_u16 with dh^2*0x10001 biases
// (no cross-half carry since 65471+16=65487<65536). Guard: searched set is
// {|dh|<=4, |dx|<=63}; complement d^2 >= min(25,4096) > 16, so any best<=16 is
// exact and best>16 triggers the exact fallback (statistically never taken:
// needs an all-ones disk of radius 5, P ~ 2^-78 per pixel).
__global__ __launch_bounds__(BLOCK, 8) void fused_kernel(const float* __restrict__ inp,
                                                         const float* __restrict__ tgt,
                                                         WS* __restrict__ ws) {
    __shared__ unsigned long long zm[LROWS][10];   // 1.3 KB zeros-mask (sentinel cols 0/9)
    __shared__ unsigned short Dd[LROWS][W];        // 16 KB clamped d^2 row profiles
    __shared__ float4 csh[4][128];                 // 8 KB per-(group,y4) column sums
    __shared__ float4 ssum[BLOCK / 64];
    __shared__ unsigned smax[BLOCK / 64];

    int bid  = blockIdx.x;        // 0..1023
    int b    = bid >> 6;          // image
    int tile = bid & 63;          // 64 tiles per image
    int h0   = tile * TILE_H;
    int tid  = threadIdx.x;
    int wave = tid >> 6, lane = tid & 63;
    const float* img = tgt + (size_t)b * IMG;

    // ========== loss phase: stream this block's 8-row slab (HBM-bound) ==========
    size_t base4 = (size_t)b * (IMG / 4) + (size_t)tile * (TILE_H * W / 4);
    const float4* x4 = (const float4*)inp + base4;
    const float4* t4 = (const float4*)tgt + base4;

    // hoist all 4 loads before processing (memory-level parallelism)
    float4 xv0 = x4[tid], xv1 = x4[tid + 512];
    float4 tv0 = t4[tid], tv1 = t4[tid + 512];

    float s0 = 0.f, s1 = 0.f, s2 = 0.f, s3 = 0.f;
    float4 ct = make_float4(0.f, 0.f, 0.f, 0.f);   // column sums for this thread's y4
    #pragma unroll
    for (int k = 0; k < 2; ++k) {                  // 1024 float4 / 512 threads
        float4 xv = k ? xv1 : xv0;
        float4 tv = k ? tv1 : tv0;
        { float d = xv.x - tv.x; float e2 = d * d; s0 += e2; ct.x += tv.x * e2;
          float p = 1.0f / (1.0f + __expf(-xv.x)); s1 += p * tv.x; s2 += p; s3 += tv.x; }
        { float d = xv.y - tv.y; float e2 = d * d; s0 += e2; ct.y += tv.y * e2;
          float p = 1.0f / (1.0f + __expf(-xv.y)); s1 += p * tv.y; s2 += p; s3 += tv.y; }
        { float d = xv.z - tv.z; float e2 = d * d; s0 += e2; ct.z += tv.z * e2;
          float p = 1.0f / (1.0f + __expf(-xv.z)); s1 += p * tv.z; s2 += p; s3 += tv.z; }
        { float d = xv.w - tv.w; float e2 = d * d; s0 += e2; ct.w += tv.w * e2;
          float p = 1.0f / (1.0f + __expf(-xv.w)); s1 += p * tv.w; s2 += p; s3 += tv.w; }
    }
    csh[tid >> 7][tid & 127] = ct;
    #pragma unroll
    for (int o = 32; o > 0; o >>= 1) {
        s0 += __shfl_down(s0, o); s1 += __shfl_down(s1, o);
        s2 += __shfl_down(s2, o); s3 += __shfl_down(s3, o);
    }
    if (lane == 0) ssum[wave] = make_float4(s0, s1, s2, s3);

    // ========== EDT phase 1: ballot-pack zeros-mask (core rows L1-hot) ==========
    // disjoint LDS from csh/ssum -> no barrier needed before this
    for (int wi = wave; wi < LROWS * 8; wi += BLOCK / 64) {   // 16 units/wave
        int lr = wi >> 3, wc = wi & 7;
        int gh = h0 - APRON + lr;
        unsigned long long m = 0ULL;
        if (gh >= 0 && gh < W) {
            float v = img[(gh << 9) + (wc << 6) + lane];
            m = __ballot(v == 0.0f);
        }
        if (lane == 0) zm[lr][wc + 1] = m;
    }
    if (tid < LROWS) { zm[tid][0] = 0ULL; zm[tid][9] = 0ULL; }
    __syncthreads();   // barrier 1: zm + csh + ssum ready

    // ========== EDT phase 2: row profiles, clamped d^2 as u16 ==========
    for (int u = wave; u < LROWS * 8; u += BLOCK / 64) {   // 16 units/wave
        int lr = u >> 3, wc = u & 7;
        unsigned long long Wm = zm[lr][wc];
        unsigned long long Wc = zm[lr][wc + 1];
        unsigned long long Wp = zm[lr][wc + 2];
        int off = lane;
        unsigned long long wr = (Wc >> off) | (off ? (Wp << (64 - off)) : 0ULL);
        int dr = wr ? __builtin_ctzll(wr) : 1000;
        unsigned long long vl = off ? ((Wc << (64 - off)) | (Wm >> off)) : Wm;
        int dl = vl ? (1 + __builtin_clzll(vl)) : 1000;
        int d = min(min(dr, dl), 1000);
        int dd = min(d * d, 65471);              // 65471 + dh^2(<=16) fits u16
        Dd[lr][(wc << 6) + lane] = (unsigned short)dd;
    }

    // ---- C-combine AFTER phase 2: atomics fire-and-forget, off the
    //      barrier-2 critical path (nothing reads C until final_kernel) ----
    if (tid < 128) {
        float4 a = csh[0][tid];
        #pragma unroll
        for (int g = 1; g < 4; ++g) {
            float4 c = csh[g][tid];
            a.x += c.x; a.y += c.y; a.z += c.z; a.w += c.w;
        }
        float* Cb = ws->C + (b << 9) + (tid << 2);
        atomicAdd(Cb + 0, a.x);
        atomicAdd(Cb + 1, a.y);
        atomicAdd(Cb + 2, a.z);
        atomicAdd(Cb + 3, a.w);
    } else if (tid == 128) {
        float4 a = ssum[0];
        #pragma unroll
        for (int i = 1; i < BLOCK / 64; ++i) {
            a.x += ssum[i].x; a.y += ssum[i].y; a.z += ssum[i].z; a.w += ssum[i].w;
        }
        ws->partial[bid] = a;
    }
    __syncthreads();   // barrier 2: Dd ready

    // ========== EDT phase 3: register-column packed combine ==========
    // thread -> y-pair p = tid & 255, output-row group q = tid >> 8 (rows 4q..4q+3)
    int p = tid & 255;
    int q = tid >> 8;                                    // 0..1
    const unsigned* Dd32 = (const unsigned*)&Dd[0][0];   // 256 u32 per row
    const unsigned* basep = Dd32 + (q << 10) + p;        // row 4q, column p
    unsigned col[12];
    #pragma unroll
    for (int j = 0; j < 12; ++j) col[j] = basep[j * 256];

    unsigned best[4];
    #pragma unroll
    for (int m = 0; m < 4; ++m) {
        unsigned bb = 0xFFFFFFFFu;
        #pragma unroll
        for (int j = 0; j <= 8; ++j) {
            unsigned dh2 = (unsigned)((j - 4) * (j - 4));
            bb = pk_min_u16(bb, col[m + j] + dh2 * 0x00010001u);
        }
        best[m] = bb;
    }
    unsigned bpk = pk_max_u16(pk_max_u16(best[0], best[1]), pk_max_u16(best[2], best[3]));
    unsigned tmax = max(bpk & 0xFFFFu, bpk >> 16);

    // ---- rare exact correction (statistically never taken) ----
    if (__builtin_expect(tmax > 16u, 0)) {
        tmax = 0;
        for (int m = 0; m < 4; ++m) {
            int k = (q << 2) + m;
            unsigned nb = 0;
            for (int half = 0; half < 2; ++half) {
                int y = (p << 1) + half;
                int bb = 1 << 30;
                for (int j = 0; j <= 8; ++j)
                    bb = min(bb, (j - 4) * (j - 4) + (int)Dd[k + j][y]);
                if (bb > 16) bb = exact_best(img, h0 + k, y);   // clamped -> true >16 -> exact
                tmax = max(tmax, (unsigned)bb);
                nb |= ((unsigned)bb & 0xFFFFu) << (half * 16);
            }
            best[m] = nb;
        }
    }

    // rows[b, h=b, :] lives in tile b>>3, local row b&7, group q=(b>>2)&1, m=b&3
    if (tile == (b >> 3) && q == ((b >> 2) & 1)) {
        unsigned rb = best[b & 3];
        ws->rows[(b << 9) + (p << 1)]     = sqrtf((float)(rb & 0xFFFFu));
        ws->rows[(b << 9) + (p << 1) + 1] = sqrtf((float)(rb >> 16));
    }

    // block max (int d^2; sqrt is monotone) -> atomicMax
    #pragma unroll
    for (int o = 32; o > 0; o >>= 1) tmax = max(tmax, (unsigned)__shfl_down(tmax, o));
    if (lane == 0) smax[wave] = tmax;
    __syncthreads();   // barrier 3: smax ready
    if (tid == 0) {
        unsigned bm = smax[0];
        #pragma unroll
        for (int i = 1; i < BLOCK / 64; ++i) bm = max(bm, smax[i]);
        atomicMax(&ws->vmax[b], bm);
    }
}

// Single-block finalize:
//   wmse_sum = sum_{b,y} C[b,y]*(v_b - rows[b,y]) + EPS_W * E   (all terms >= 0)
//   dice     = 1 - (2*s1 + 1e-6)/(s2 + s3 + 1e-6)
#define FBLOCK 256
__global__ __launch_bounds__(FBLOCK) void final_kernel(const WS* __restrict__ ws,
                                                       float* __restrict__ out) {
    int tid = threadIdx.x;
    __shared__ float vsh[16];
    if (tid < 16) vsh[tid] = sqrtf((float)ws->vmax[tid]);
    __syncthreads();

    double wm = 0.0;
    #pragma unroll
    for (int j = 0; j < (NB * W) / FBLOCK; ++j) {   // 32 cells/thread
        int cell = tid + j * FBLOCK;
        wm += (double)ws->C[cell] * (double)(vsh[cell >> 9] - ws->rows[cell]);
    }
    double e = 0, s1 = 0, s2 = 0, s3 = 0;
    #pragma unroll
    for (int j = 0; j < GRID / FBLOCK; ++j) {       // 4
        float4 p = ws->partial[tid + j * FBLOCK];
        e += p.x; s1 += p.y; s2 += p.z; s3 += p.w;
    }

    #pragma unroll
    for (int o = 32; o > 0; o >>= 1) {
        wm += __shfl_down(wm, o); e  += __shfl_down(e, o);
        s1 += __shfl_down(s1, o); s2 += __shfl_down(s2, o); s3 += __shfl_down(s3, o);
    }
    __shared__ double shd[FBLOCK / 64][5];
    int lane = tid & 63, wid = tid >> 6;
    if (lane == 0) { shd[wid][0] = wm; shd[wid][1] = e;
                     shd[wid][2] = s1; shd[wid][3] = s2; shd[wid][4] = s3; }
    __syncthreads();
    if (tid == 0) {
        double a0 = 0, a1 = 0, a2 = 0, a3 = 0, a4 = 0;
        #pragma unroll
        for (int i = 0; i < FBLOCK / 64; ++i) {
            a0 += shd[i][0]; a1 += shd[i][1]; a2 += shd[i][2]; a3 += shd[i][3]; a4 += shd[i][4];
        }
        double wmse = (a0 + 0.001 * a1) / (double)NPIX;
        out[0] = (float)(0.6 * wmse);
        out[1] = (float)(1.0 - (2.0 * a2 + 1e-6) / (a3 + a4 + 1e-6));
    }
}

extern "C" void kernel_launch(void* const* d_in, const int* in_sizes, int n_in,
                              void* d_out, int out_size, void* d_ws, size_t ws_size,
                              hipStream_t stream) {
    const float* inp = (const float*)d_in[0];
    const float* tgt = (const float*)d_in[1];
    float* out = (float*)d_out;
    WS* ws = (WS*)d_ws;

    // zero vmax + C (contiguous at struct start); rows/partial fully overwritten
    hipMemsetAsync(d_ws, 0, MEMSET_BYTES, stream);
    fused_kernel<<<GRID, BLOCK, 0, stream>>>(inp, tgt, ws);
    final_kernel<<<1, FBLOCK, 0, stream>>>(ws, out);
}

// Round 8
// 90.765 us; speedup vs baseline: 1.1136x; 1.1136x over previous
//
#include <hip/hip_runtime.h>

#define W      512
#define IMG    (512 * 512)
#define NB     16
#define NPIX   (NB * IMG)

// ---- geometry: 512 uniform hybrid blocks of 1024 threads (round-6 proven) ----
#define TILE_H 16
#define APRON  4
#define LROWS  (TILE_H + 2 * APRON)       // 24
#define BLOCK  1024
#define GRID   (NB * (W / TILE_H))        // 512 == 256 CUs * 2 blocks/CU (100% cap)

// Store-only workspace: every field is fully written each launch -> NO memset.
// counter is never reset: the (old+1)&15==0 test fires exactly once per launch
// for any (poisoned) starting value, since 16 consecutive values hit each
// residue class mod 16 exactly once.
struct WS {
    float rows[NB * W];               // w_edt[b, h=b, y] (sqrt'd), tile-0 blocks
    float4 colpart[GRID][128];        // per-block column sums: C contribution
    float4 partial[GRID][16];         // per-(block,wave): e, p*t, p, t
    unsigned wsmax[GRID][16];         // per-(block,wave) max int d^2
    double img5[NB][5];               // per-image finals: wm, e, pt, p, t
    unsigned counter;                 // monotone arrival counter (mod-16 trick)
};

__device__ __forceinline__ unsigned pk_min_u16(unsigned a, unsigned b) {
    unsigned r; asm("v_pk_min_u16 %0, %1, %2" : "=v"(r) : "v"(a), "v"(b)); return r;
}
__device__ __forceinline__ unsigned pk_max_u16(unsigned a, unsigned b) {
    unsigned r; asm("v_pk_max_u16 %0, %1, %2" : "=v"(r) : "v"(a), "v"(b)); return r;
}

// Exact full-image nearest-zero scan (rare fallback; also handles no-zero case -> BIG)
__device__ int exact_best(const float* __restrict__ img, int h, int y) {
    int best = 100000000;   // reference BIG when no zeros exist
    for (int gh = 0; gh < W; ++gh) {
        int dhh = gh - h;
        if (dhh * dhh >= best) continue;
        const float* rp = img + (gh << 9);
        for (int yy = 0; yy < W; ++yy)
            if (rp[yy] == 0.0f) {
                int dx = yy - y;
                best = min(best, dhh * dhh + dx * dx);
            }
    }
    return best;
}

// Fused kernel (round-6 body, store-only outputs, 2 barriers):
// loss stream + in-register core-row mask packing + apron prefetch; phase 2
// stores CLAMPED d^2 (<=65471) as u16; phase 3 register-column packed combine
// (4x9 v_pk_min_u16, dh^2*0x10001 bias, no cross-half carry: 65471+16<65536).
// Guard: searched set {|dh|<=4, |dx|<=63}; complement d^2 >= 25 > 16, so
// best<=16 is exact; best>16 triggers the exact fallback (P ~ 2^-78/pixel).
__global__ __launch_bounds__(BLOCK, 8) void fused_kernel(const float* __restrict__ inp,
                                                         const float* __restrict__ tgt,
                                                         WS* __restrict__ ws) {
    __shared__ unsigned long long zm[LROWS][10];   // 1.9 KB zeros-mask (sentinel cols 0/9)
    __shared__ unsigned short Dd[LROWS][W];        // 24 KB clamped d^2 row profiles
    __shared__ float4 csh[8][128];                 // 16 KB per-(group,y4) column sums

    int bid  = blockIdx.x;        // 0..511
    int b    = bid >> 5;          // image
    int tile = bid & 31;
    int h0   = tile * TILE_H;
    int tid  = threadIdx.x;
    int wave = tid >> 6, lane = tid & 63;
    const float* img = tgt + (size_t)b * IMG;

    // ---- apron prefetch: 64 (row,word) units over 16 waves = 4 per wave ----
    float av[4];
    #pragma unroll
    for (int j = 0; j < 4; ++j) {
        int aa = (wave << 2) + j;
        int ar = aa >> 3;                       // 0..7 apron-row index
        int lr = ar < 4 ? ar : ar + 16;         // 0..3 top, 20..23 bottom
        int wc = aa & 7;
        int gh = h0 - APRON + lr;
        av[j] = (gh >= 0 && gh < W) ? img[(gh << 9) + (wc << 6) + lane] : 1.0f;
    }

    // ========== loss phase: stream this block's 16-row slab (HBM-bound) ==========
    size_t base4 = (size_t)b * (IMG / 4) + (size_t)tile * (TILE_H * W / 4);
    const float4* x4 = (const float4*)inp + base4;
    const float4* t4 = (const float4*)tgt + base4;

    float s0 = 0.f, s1 = 0.f, s2 = 0.f, s3 = 0.f;
    float4 ct = make_float4(0.f, 0.f, 0.f, 0.f);   // column sums for this thread's y4
    #pragma unroll
    for (int k = 0; k < 2; ++k) {                  // 2048 float4 / 1024 threads
        int i = tid + (k << 10);                   // y4 = i & 127 fixed per thread
        float4 xv = x4[i];
        float4 tv = t4[i];
        { float d = xv.x - tv.x; float e2 = d * d; s0 += e2; ct.x += tv.x * e2;
          float p = 1.0f / (1.0f + __expf(-xv.x)); s1 += p * tv.x; s2 += p; s3 += tv.x; }
        { float d = xv.y - tv.y; float e2 = d * d; s0 += e2; ct.y += tv.y * e2;
          float p = 1.0f / (1.0f + __expf(-xv.y)); s1 += p * tv.y; s2 += p; s3 += tv.y; }
        { float d = xv.z - tv.z; float e2 = d * d; s0 += e2; ct.z += tv.z * e2;
          float p = 1.0f / (1.0f + __expf(-xv.z)); s1 += p * tv.z; s2 += p; s3 += tv.z; }
        { float d = xv.w - tv.w; float e2 = d * d; s0 += e2; ct.w += tv.w * e2;
          float p = 1.0f / (1.0f + __expf(-xv.w)); s1 += p * tv.w; s2 += p; s3 += tv.w; }

        // ---- pack this row-half's zero-mask in-register (free under HBM stalls) ----
        unsigned nib = (tv.x == 0.f ? 1u : 0u) | (tv.y == 0.f ? 2u : 0u)
                     | (tv.z == 0.f ? 4u : 0u) | (tv.w == 0.f ? 8u : 0u);
        unsigned long long contrib = (unsigned long long)nib << ((lane & 15) << 2);
        #pragma unroll
        for (int m = 1; m <= 8; m <<= 1) contrib |= __shfl_xor(contrib, m);
        if ((lane & 15) == 0) {
            int r = (wave >> 1) + (k << 3);
            zm[APRON + r][((wave & 1) << 2) + (lane >> 4) + 1] = contrib;
        }
    }
    csh[tid >> 7][tid & 127] = ct;
    #pragma unroll
    for (int o = 32; o > 0; o >>= 1) {
        s0 += __shfl_down(s0, o); s1 += __shfl_down(s1, o);
        s2 += __shfl_down(s2, o); s3 += __shfl_down(s3, o);
    }
    if (lane == 0) ws->partial[bid][wave] = make_float4(s0, s1, s2, s3);  // store-only

    // ---- apron ballots (prefetched values; OOB lanes forced non-zero) ----
    #pragma unroll
    for (int j = 0; j < 4; ++j) {
        int aa = (wave << 2) + j;
        int ar = aa >> 3;
        int lr = ar < 4 ? ar : ar + 16;
        int wc = aa & 7;
        unsigned long long m = __ballot(av[j] == 0.0f);
        if (lane == 0) zm[lr][wc + 1] = m;
    }
    if (tid < LROWS) { zm[tid][0] = 0ULL; zm[tid][9] = 0ULL; }
    __syncthreads();   // barrier 1: zm + csh ready

    // ========== EDT phase 2: row profiles, clamped d^2 as u16 ==========
    for (int u = wave; u < LROWS * 8; u += BLOCK / 64) {   // 12 units/wave
        int lr = u >> 3, wc = u & 7;
        unsigned long long Wm = zm[lr][wc];
        unsigned long long Wc = zm[lr][wc + 1];
        unsigned long long Wp = zm[lr][wc + 2];
        int off = lane;
        unsigned long long wr = (Wc >> off) | (off ? (Wp << (64 - off)) : 0ULL);
        int dr = wr ? __builtin_ctzll(wr) : 1000;
        unsigned long long vl = off ? ((Wc << (64 - off)) | (Wm >> off)) : Wm;
        int dl = vl ? (1 + __builtin_clzll(vl)) : 1000;
        int d = min(min(dr, dl), 1000);
        int dd = min(d * d, 65471);              // 65471 + dh^2(<=16) fits u16
        Dd[lr][(wc << 6) + lane] = (unsigned short)dd;
    }

    // ---- colpart store (threads 0..127): plain store, fire-and-forget ----
    if (tid < 128) {
        float4 a = csh[0][tid];
        #pragma unroll
        for (int g = 1; g < 8; ++g) {
            float4 c = csh[g][tid];
            a.x += c.x; a.y += c.y; a.z += c.z; a.w += c.w;
        }
        ws->colpart[bid][tid] = a;
    }
    __syncthreads();   // barrier 2: Dd ready

    // ========== EDT phase 3: register-column packed combine ==========
    int p = tid & 255;
    int q = tid >> 8;                                    // 0..3
    const unsigned* Dd32 = (const unsigned*)&Dd[0][0];   // 256 u32 per row
    const unsigned* basep = Dd32 + (q << 10) + p;        // row 4q, column p
    unsigned col[12];
    #pragma unroll
    for (int j = 0; j < 12; ++j) col[j] = basep[j * 256];

    unsigned best[4];
    #pragma unroll
    for (int m = 0; m < 4; ++m) {
        unsigned bb = 0xFFFFFFFFu;
        #pragma unroll
        for (int j = 0; j <= 8; ++j) {
            unsigned dh2 = (unsigned)((j - 4) * (j - 4));
            bb = pk_min_u16(bb, col[m + j] + dh2 * 0x00010001u);
        }
        best[m] = bb;
    }
    unsigned bpk = pk_max_u16(pk_max_u16(best[0], best[1]), pk_max_u16(best[2], best[3]));
    unsigned tmax = max(bpk & 0xFFFFu, bpk >> 16);

    // ---- rare exact correction (statistically never taken) ----
    if (__builtin_expect(tmax > 16u, 0)) {
        tmax = 0;
        for (int m = 0; m < 4; ++m) {
            int k = (q << 2) + m;
            unsigned nb = 0;
            for (int half = 0; half < 2; ++half) {
                int y = (p << 1) + half;
                int bb = 1 << 30;
                for (int j = 0; j <= 8; ++j)
                    bb = min(bb, (j - 4) * (j - 4) + (int)Dd[k + j][y]);
                if (bb > 16) bb = exact_best(img, h0 + k, y);   // clamped -> true >16 -> exact
                tmax = max(tmax, (unsigned)bb);
                nb |= ((unsigned)bb & 0xFFFFu) << (half * 16);
            }
            best[m] = nb;
        }
    }

    // rows[b, h=b, :] lives in tile 0, local row k=b
    if (tile == 0 && q == (b >> 2)) {
        unsigned rb = best[b & 3];
        ws->rows[(b << 9) + (p << 1)]     = sqrtf((float)(rb & 0xFFFFu));
        ws->rows[(b << 9) + (p << 1) + 1] = sqrtf((float)(rb >> 16));
    }

    // per-wave max (int d^2; sqrt is monotone) -> plain store, no barrier 3
    #pragma unroll
    for (int o = 32; o > 0; o >>= 1) tmax = max(tmax, (unsigned)__shfl_down(tmax, o));
    if (lane == 0) ws->wsmax[bid][wave] = tmax;
}

// Finalize: 16 blocks, one per image. Block b reduces its image's wsmax ->
// v_b, partial -> (e,pt,p,t), colpart x (v - rows) -> wm_b; stores 5 doubles.
// The last-arriving block (mod-16 counter, needs no init) combines all 16.
#define FBLOCK 256
__global__ __launch_bounds__(FBLOCK) void final_kernel(WS* __restrict__ ws,
                                                       float* __restrict__ out) {
    int b    = blockIdx.x;
    int tid  = threadIdx.x;
    int lane = tid & 63, wave = tid >> 6;
    __shared__ unsigned vsh4[4];
    __shared__ double shd[4][5];
    __shared__ double fin[80];
    __shared__ int sh_last;

    // ---- v_b: max over 32 tiles x 16 waves = 512 entries ----
    unsigned vm = 0;
    #pragma unroll
    for (int j = 0; j < 2; ++j) {
        int idx = (tid << 1) + j;            // 0..511
        vm = max(vm, ws->wsmax[(b << 5) + (idx >> 4)][idx & 15]);
    }
    #pragma unroll
    for (int o = 32; o > 0; o >>= 1) vm = max(vm, (unsigned)__shfl_down(vm, o));
    if (lane == 0) vsh4[wave] = vm;
    __syncthreads();
    float v = sqrtf((float)max(max(vsh4[0], vsh4[1]), max(vsh4[2], vsh4[3])));

    // ---- scalar sums: 512 float4 partials ----
    double e = 0, t1 = 0, t2 = 0, t3 = 0;
    #pragma unroll
    for (int j = 0; j < 2; ++j) {
        int idx = (tid << 1) + j;
        float4 pp = ws->partial[(b << 5) + (idx >> 4)][idx & 15];
        e += pp.x; t1 += pp.y; t2 += pp.z; t3 += pp.w;
    }

    // ---- wm: sum_y C[b,y]*(v - rows[b,y]); thread pair (half) splits 32 tiles ----
    int y4 = tid & 127, half = tid >> 7;
    float4 acc = make_float4(0.f, 0.f, 0.f, 0.f);
    #pragma unroll
    for (int t = 0; t < 16; ++t) {
        float4 cp = ws->colpart[(b << 5) + (half << 4) + t][y4];
        acc.x += cp.x; acc.y += cp.y; acc.z += cp.z; acc.w += cp.w;
    }
    const float4 r4 = *(const float4*)&ws->rows[(b << 9) + (y4 << 2)];
    double wm = (double)acc.x * (double)(v - r4.x) + (double)acc.y * (double)(v - r4.y)
              + (double)acc.z * (double)(v - r4.z) + (double)acc.w * (double)(v - r4.w);

    // ---- block reduce the 5 sums ----
    #pragma unroll
    for (int o = 32; o > 0; o >>= 1) {
        wm += __shfl_down(wm, o); e  += __shfl_down(e, o);
        t1 += __shfl_down(t1, o); t2 += __shfl_down(t2, o); t3 += __shfl_down(t3, o);
    }
    if (lane == 0) { shd[wave][0] = wm; shd[wave][1] = e;
                     shd[wave][2] = t1; shd[wave][3] = t2; shd[wave][4] = t3; }
    __syncthreads();
    if (tid == 0) {
        double a0 = 0, a1 = 0, a2 = 0, a3 = 0, a4 = 0;
        #pragma unroll
        for (int i = 0; i < 4; ++i) {
            a0 += shd[i][0]; a1 += shd[i][1]; a2 += shd[i][2]; a3 += shd[i][3]; a4 += shd[i][4];
        }
        ws->img5[b][0] = a0; ws->img5[b][1] = a1; ws->img5[b][2] = a2;
        ws->img5[b][3] = a3; ws->img5[b][4] = a4;
        __threadfence();                       // release img5 before arrival
        unsigned old = atomicAdd(&ws->counter, 1u);
        sh_last = (((old + 1) & 15) == 0);     // exactly one hit per launch
    }
    __syncthreads();
    if (!sh_last) return;

    // ---- last block: combine 16 x 5 doubles ----
    __threadfence();                           // acquire
    if (tid < 80) fin[tid] = ((volatile double*)ws->img5)[tid];
    __syncthreads();
    if (tid == 0) {
        double a0 = 0, a1 = 0, a2 = 0, a3 = 0, a4 = 0;
        #pragma unroll
        for (int i = 0; i < 16; ++i) {
            a0 += fin[i * 5 + 0]; a1 += fin[i * 5 + 1]; a2 += fin[i * 5 + 2];
            a3 += fin[i * 5 + 3]; a4 += fin[i * 5 + 4];
        }
        double wmse = (a0 + 0.001 * a1) / (double)NPIX;
        out[0] = (float)(0.6 * wmse);
        out[1] = (float)(1.0 - (2.0 * a2 + 1e-6) / (a3 + a4 + 1e-6));
    }
}

extern "C" void kernel_launch(void* const* d_in, const int* in_sizes, int n_in,
                              void* d_out, int out_size, void* d_ws, size_t ws_size,
                              hipStream_t stream) {
    const float* inp = (const float*)d_in[0];
    const float* tgt = (const float*)d_in[1];
    float* out = (float*)d_out;
    WS* ws = (WS*)d_ws;

    // no memset: all WS fields are fully written each launch; the arrival
    // counter uses the mod-16 trick so poison garbage is harmless.
    fused_kernel<<<GRID, BLOCK, 0, stream>>>(inp, tgt, ws);
    final_kernel<<<NB, FBLOCK, 0, stream>>>(ws, out);
}